// Round 12
// baseline (162.649 us; speedup 1.0000x reference)
//
#include <hip/hip_runtime.h>
#include <hip/hip_bf16.h>
#include <stdint.h>

typedef __hip_bfloat16 bf16_t;
typedef __attribute__((ext_vector_type(8))) __bf16 bf16x8;
typedef __attribute__((ext_vector_type(4))) float f32x4;
typedef __attribute__((ext_vector_type(8))) unsigned short ushort8;
typedef __attribute__((ext_vector_type(2))) unsigned long long u64x2;

#define BM 256
#define BN 256
#define BK 64
#define THREADS 512
#define OPBYTES 32768   // one operand per buf: 256 rows x 128 B
#define BUFBYTES 65536  // A + B
#define LDS_TOTAL 131072

// ---------------- fused quantize: q = rint(v*100)/100, cast to bf16 ----------------
__global__ __launch_bounds__(256) void quant2_bf16_kernel(
    const float* __restrict__ x, const float* __restrict__ w,
    bf16_t* __restrict__ q, long axn8, long totn8) {
  long idx = (long)blockIdx.x * blockDim.x + threadIdx.x;
  long stride = (long)gridDim.x * blockDim.x;
  for (long i = idx; i < totn8; i += stride) {
    const float* src = (i < axn8) ? (x + i * 8) : (w + (i - axn8) * 8);
    const float4* p = reinterpret_cast<const float4*>(src);
    float4 v0 = p[0];
    float4 v1 = p[1];
    float vv[8] = {v0.x, v0.y, v0.z, v0.w, v1.x, v1.y, v1.z, v1.w};
    ushort8 r;
#pragma unroll
    for (int j = 0; j < 8; ++j) {
      float qq = rintf(vv[j] * 100.0f) / 100.0f;  // half-to-even, matches jnp.round
      __hip_bfloat16 h = __float2bfloat16(qq);
      r[j] = __builtin_bit_cast(unsigned short, h);
    }
    u64x2 u = __builtin_bit_cast(u64x2, r);
    unsigned long long* dst = reinterpret_cast<unsigned long long*>(q + i * 8);
    __hip_atomic_store(dst + 0, u[0], __ATOMIC_RELAXED, __HIP_MEMORY_SCOPE_AGENT);
    __hip_atomic_store(dst + 1, u[1], __ATOMIC_RELAXED, __HIP_MEMORY_SCOPE_AGENT);
  }
}

// ---------------- fallback ----------------
__global__ void naive_kernel(const float* __restrict__ x, const float* __restrict__ W,
                             const float* __restrict__ b, float* __restrict__ out,
                             int M, int N, int K) {
  int o = blockIdx.x * blockDim.x + threadIdx.x;
  int m = blockIdx.y;
  if (o >= N || m >= M) return;
  float s = 0.f;
  for (int k = 0; k < K; ++k) {
    float qx = rintf(x[(size_t)m * K + k] * 100.f) / 100.f;
    float qw = rintf(W[(size_t)o * K + k] * 100.f) / 100.f;
    s += qx * qw;
  }
  float v = s + b[o];
  __hip_atomic_store(out + (size_t)m * N + o, v, __ATOMIC_RELAXED,
                     __HIP_MEMORY_SCOPE_AGENT);
}

__device__ __forceinline__ void gload_lds16(const bf16_t* g, const char* l) {
  __builtin_amdgcn_global_load_lds(
      (const __attribute__((address_space(1))) unsigned int*)g,
      (__attribute__((address_space(3))) unsigned int*)l, 16, 0, 0);
}

#define BARRIER()                               \
  do {                                          \
    asm volatile("" ::: "memory");              \
    __builtin_amdgcn_s_barrier();               \
    asm volatile("" ::: "memory");              \
  } while (0)
#define VM6() asm volatile("s_waitcnt vmcnt(6)" ::: "memory")
#define VM0() asm volatile("s_waitcnt vmcnt(0)" ::: "memory")

// ---------------- bf16 GEMM, B^T input: C[m][n] = sum_k A[m][k]*B[n][k] + bias[n]
// ROUND 12 = r8 + (a) kk-OUTER MFMA ordering, (b) EVEN stage spread (2 loads
// per phase) with deep vmcnt(6) cover.
// (a) r8's kk-inner nest put a dependent MFMA pair (same acc) back-to-back:
//     MFMA latency (~20cy) >> issue (~5cy) -> matrix-pipe latency stalls.
//     kk-outer gives 7 independent MFMAs between each write/read of an acc.
// (b) r8 bunched 4 DMA loads into the phases that also carry read bursts;
//     m201 stages exactly 2/phase. New schedule (STAGE call = 2 loads/thread):
//       ph1: b1.A1(t1)  ph2: b0.B0(t2)  ph3: b0.B1(t2)  ph4: b0.A0(t2)+VM6
//       ph5: b0.A1(t2)  ph6: b1.B0(t3)  ph7: b1.B1(t3)  ph8: b1.A0(t3)+VM6
// Reads (phase-top, consumed same phase): ph1 blo+Alo(b0); ph2 bhi(b0);
//   ph3 Ahi(b0); ph4 none; ph5-8 mirror on b1.
// WAR (>=1 barrier between a region's last read and its overwrite):
//   b1.A1 read ph7(prev) -> staged ph1; b0.B0 read ph1 -> ph2; b0.B1 read ph2
//   -> ph3; b0.A0 read ph1 -> ph4; b0.A1 read ph3 -> ph5; b1.B0 read ph5 ->
//   ph6; b1.B1 read ph6 -> ph7; b1.A0 read ph5 -> ph8. All hold.
// vmcnt ledger (loads, oldest-first; steady state entering ph1: 6 in flight =
//   prev ph6,7,8): ph4 VM6: 14 outstanding -> retire 8 = prev{6,7,8}+ph1 =
//   EXACTLY tile t1 (B0,B1,A0,A1), needed by ph5-8; all 4-7 phases old.
//   ph8 VM6: 14 -> retire 8 = ph2,3,4,5 = EXACTLY tile t2, needed next ph1/ph3.
//   Recurrence closes (6 in flight at iter end). Prologue: t0 full + t1
//   {B0,B1,A0} = 14 loads, VM6 retires t0's 8, keeps t1's 6. LAST iter PEELED:
//   only ph1's stage (b1.A1(nt-1), still needed by ph7); VM0 at ph4.
// LDS swizzle: 128B rows, stored slot = slot ^ (row&7) (0 conflicts measured
// r2-r11). global_load_lds dest linear; swizzle on the global SOURCE (rule #21).
__global__ __launch_bounds__(THREADS, 2) void gemm_bt_bf16(
    const bf16_t* __restrict__ A,   // [M][K]
    const bf16_t* __restrict__ B,   // [N][K]
    const float* __restrict__ bias, // [N]
    float* __restrict__ C,          // [M][N]
    int M, int N, int K) {
  extern __shared__ char lds[];

  const int tid = threadIdx.x;
  const int lane = tid & 63;
  const int wave = tid >> 6;  // 0..7
  const int wm = wave >> 2;   // 0..1 -> output rows wm*128..+128
  const int wn = wave & 3;    // 0..3 -> output cols wn*64..+64
  const int lr = lane & 15;
  const int lg = lane >> 4;

  // XCD-aware bijective swizzle (nwg % 8 == 0 guaranteed by tiled_ok)
  int nbn = N / BN;
  int nwg = gridDim.x;
  int bid = blockIdx.x;
  int swz = bid;
  if ((nwg & 7) == 0) {
    int cpx = nwg >> 3;
    swz = (bid & 7) * cpx + (bid >> 3);
  }
  const int brow = (swz / nbn) * BM;
  const int bcol = (swz % nbn) * BN;

  // ds_read byte offsets within an operand region (kk=0; kk=1 is ^64)
  int aoffs[8], boffs[4];
#pragma unroll
  for (int m = 0; m < 8; ++m) {
    int r = wm * 128 + m * 16 + lr;
    aoffs[m] = r * 128 + (((lg) ^ (r & 7)) << 4);
  }
#pragma unroll
  for (int n = 0; n < 4; ++n) {
    int r = wn * 64 + n * 16 + lr;
    boffs[n] = r * 128 + (((lg) ^ (r & 7)) << 4);
  }

  f32x4 acc[8][4];
#pragma unroll
  for (int m = 0; m < 8; ++m)
#pragma unroll
    for (int n = 0; n < 4; ++n) acc[m][n] = (f32x4){0.f, 0.f, 0.f, 0.f};

  const int nt = K / BK;

  auto STAGE_A = [&](int h, int kt, int q) {
#pragma unroll
    for (int i = 0; i < 2; ++i) {
      int row = h * 128 + i * 64 + (tid >> 3);
      int L = q * BUFBYTES + row * 128 + ((tid & 7) << 4);
      int slot = (tid & 7) ^ (row & 7);
      gload_lds16(A + (size_t)(brow + row) * K + (size_t)kt * 64 + slot * 8,
                  lds + L);
    }
  };
  auto STAGE_B = [&](int h, int kt, int q) {
#pragma unroll
    for (int i = 0; i < 2; ++i) {
      int row = h * 128 + i * 64 + (tid >> 3);
      int L = q * BUFBYTES + OPBYTES + row * 128 + ((tid & 7) << 4);
      int slot = (tid & 7) ^ (row & 7);
      gload_lds16(B + (size_t)(bcol + row) * K + (size_t)kt * 64 + slot * 8,
                  lds + L);
    }
  };

  bf16x8 aq[8], blo[4], bhi[4];  // A quadrant [mm][kk]; B quadrants [nn][kk]
  auto READ_A = [&](int q, int mh) {
#pragma unroll
    for (int mm = 0; mm < 4; ++mm) {
      int off = q * BUFBYTES + aoffs[mh * 4 + mm];
      aq[mm * 2 + 0] = *reinterpret_cast<const bf16x8*>(lds + off);
      aq[mm * 2 + 1] = *reinterpret_cast<const bf16x8*>(lds + (off ^ 64));
    }
  };
  auto READ_B = [&](int q, int nh, bf16x8* dst) {
#pragma unroll
    for (int nn = 0; nn < 2; ++nn) {
      int off = q * BUFBYTES + OPBYTES + boffs[nh * 2 + nn];
      dst[nn * 2 + 0] = *reinterpret_cast<const bf16x8*>(lds + off);
      dst[nn * 2 + 1] = *reinterpret_cast<const bf16x8*>(lds + (off ^ 64));
    }
  };
  // kk-OUTER: all 8 acc-independent MFMAs of k-slice 0 issue before any
  // k-slice-1 MFMA reads the same acc -> no back-to-back dependent MFMAs.
  auto MMA = [&](int mh, int nh, const bf16x8* bb) {
    __builtin_amdgcn_s_setprio(1);
#pragma unroll
    for (int kk = 0; kk < 2; ++kk)
#pragma unroll
      for (int mm = 0; mm < 4; ++mm)
#pragma unroll
        for (int nn = 0; nn < 2; ++nn)
          acc[mh * 4 + mm][nh * 2 + nn] = __builtin_amdgcn_mfma_f32_16x16x32_bf16(
              aq[mm * 2 + kk], bb[nn * 2 + kk], acc[mh * 4 + mm][nh * 2 + nn],
              0, 0, 0);
    __builtin_amdgcn_s_setprio(0);
  };

  // Prologue: t0 full + t1 {B0,B1,A0} (14 loads); VM6 retires t0's 8,
  // keeps t1's 6 in flight (steady-state ph1 entry condition).
  STAGE_B(0, 0, 0); STAGE_B(1, 0, 0); STAGE_A(0, 0, 0); STAGE_A(1, 0, 0);
  STAGE_B(0, 1, 1); STAGE_B(1, 1, 1); STAGE_A(0, 1, 1);
  VM6();
  BARRIER();

  const int np = nt >> 1;
  for (int p = 0; p < np - 1; ++p) {
    const int t1 = 2 * p + 1, t2 = 2 * p + 2, t3 = 2 * p + 3;
    // ph1: buf0 (m-lo,n-lo); stage b1.A1(t1) (completes tile t1)
    READ_B(0, 0, blo); READ_A(0, 0);
    STAGE_A(1, t1, 1);
    MMA(0, 0, blo);
    BARRIER();
    // ph2: (m-lo,n-hi); stage b0.B0(t2)
    READ_B(0, 1, bhi);
    STAGE_B(0, t2, 0);
    MMA(0, 1, bhi);
    BARRIER();
    // ph3: (m-hi,n-hi); stage b0.B1(t2)
    READ_A(0, 1);
    STAGE_B(1, t2, 0);
    MMA(1, 1, bhi);
    BARRIER();
    // ph4: (m-hi,n-lo); stage b0.A0(t2); VM6 retires tile t1 (4-7 phases old)
    STAGE_A(0, t2, 0);
    MMA(1, 0, blo);
    VM6();
    BARRIER();
    // ph5: buf1 (m-lo,n-lo); stage b0.A1(t2) (completes tile t2)
    READ_B(1, 0, blo); READ_A(1, 0);
    STAGE_A(1, t2, 0);
    MMA(0, 0, blo);
    BARRIER();
    // ph6: stage b1.B0(t3)
    READ_B(1, 1, bhi);
    STAGE_B(0, t3, 1);
    MMA(0, 1, bhi);
    BARRIER();
    // ph7: stage b1.B1(t3)
    READ_A(1, 1);
    STAGE_B(1, t3, 1);
    MMA(1, 1, bhi);
    BARRIER();
    // ph8: stage b1.A0(t3); VM6 retires tile t2 (needed next ph1)
    STAGE_A(0, t3, 1);
    MMA(1, 0, blo);
    VM6();
    BARRIER();
  }

  // Peeled final iteration (t0=nt-2, t1=nt-1): only ph1's stage (b1.A1(t1),
  // consumed at ph7); VM0 at ph4 drains it plus the carried 6.
  {
    const int t1 = nt - 1;
    READ_B(0, 0, blo); READ_A(0, 0);
    STAGE_A(1, t1, 1);
    MMA(0, 0, blo);
    BARRIER();
    READ_B(0, 1, bhi);
    MMA(0, 1, bhi);
    BARRIER();
    READ_A(0, 1);
    MMA(1, 1, bhi);
    BARRIER();
    MMA(1, 0, blo);
    VM0();
    BARRIER();
    READ_B(1, 0, blo); READ_A(1, 0);
    MMA(0, 0, blo);
    BARRIER();
    READ_B(1, 1, bhi);
    MMA(0, 1, bhi);
    BARRIER();
    READ_A(1, 1);
    MMA(1, 1, bhi);
    BARRIER();
    MMA(1, 0, blo);
  }

  // Epilogue: C/D layout col=lane&15, row=(lane>>4)*4+reg  [m89/m91]
  // Agent-scope stores (replay-safe visibility past per-XCD L2).
  const int cn = lane & 15;
  const int r4 = (lane >> 4) << 2;
#pragma unroll
  for (int n = 0; n < 4; ++n) {
    const int gcol = bcol + wn * 64 + n * 16 + cn;
    const float bv = bias[gcol];
#pragma unroll
    for (int m = 0; m < 8; ++m) {
      const int grow = brow + wm * 128 + m * 16 + r4;
      float* outp = C + (size_t)grow * N + gcol;
#pragma unroll
      for (int j = 0; j < 4; ++j) {
        float v = acc[m][n][j] + bv;
        __hip_atomic_store(outp + (size_t)j * N, v, __ATOMIC_RELAXED,
                           __HIP_MEMORY_SCOPE_AGENT);
      }
    }
  }
}

extern "C" void kernel_launch(void* const* d_in, const int* in_sizes, int n_in,
                              void* d_out, int out_size, void* d_ws, size_t ws_size,
                              hipStream_t stream) {
  const float* x = (const float*)d_in[0];
  const float* W = (const float*)d_in[1];
  const float* b = (const float*)d_in[2];
  float* out = (float*)d_out;

  const int N = in_sizes[2];       // D_OUT
  const int K = in_sizes[1] / N;   // D_IN
  const int M = in_sizes[0] / K;   // B rows

  const size_t needA = (size_t)M * K * sizeof(bf16_t);
  const size_t needB = (size_t)N * K * sizeof(bf16_t);
  const bool tiled_ok = (M % BM == 0) && (N % BN == 0) && (K % (2 * BK) == 0) &&
                        (K / BK >= 2) && (ws_size >= needA + needB);
  if (!tiled_ok) {
    dim3 g((unsigned)((N + 255) / 256), (unsigned)M);
    naive_kernel<<<g, 256, 0, stream>>>(x, W, b, out, M, N, K);
    return;
  }

  bf16_t* qA = (bf16_t*)d_ws;
  bf16_t* qB = qA + (size_t)M * K;
  const long axn8 = (long)M * K / 8;
  const long totn8 = axn8 + (long)N * K / 8;
  quant2_bf16_kernel<<<2048, 256, 0, stream>>>(x, W, qA, axn8, totn8);

  (void)hipFuncSetAttribute((const void*)gemm_bt_bf16,
                            hipFuncAttributeMaxDynamicSharedMemorySize, LDS_TOTAL);

  const int nwg = (M / BM) * (N / BN);
  gemm_bt_bf16<<<nwg, THREADS, LDS_TOTAL, stream>>>(qA, qB, b, out, M, N, K);
}